// Round 1
// baseline (175.906 us; speedup 1.0000x reference)
//
#include <hip/hip_runtime.h>
#include <hip/hip_bf16.h>

// Problem constants (B,H,W,C = 32,32,32,256 -> l = 1024)
#define BATCH 32
#define L 1024
#define CD 256
#define TM 64          // pred rows per block
#define TN 64          // query cols per n-tile
#define KCHUNK 128     // K staging chunk for q
#define RT_PER_B 16    // L / TM row-tiles per batch

typedef __bf16 bf16x8 __attribute__((ext_vector_type(8)));
typedef __bf16 bf16x4 __attribute__((ext_vector_type(4)));
typedef float  f32x4  __attribute__((ext_vector_type(4)));

// Monotonic (order-preserving) float32 -> uint32 encoding
__device__ __forceinline__ unsigned int enc_f32(float f) {
    unsigned int u = __float_as_uint(f);
    return ((int)u < 0) ? ~u : (u | 0x80000000u);
}
__device__ __forceinline__ float dec_f32(unsigned int u) {
    u = (u & 0x80000000u) ? (u & 0x7FFFFFFFu) : ~u;
    return __uint_as_float(u);
}
__device__ __forceinline__ unsigned long long pmax(unsigned long long a, unsigned long long b) {
    return a > b ? a : b;
}

// Kernel 1: per (batch, row-tile) block computes M[a, :] for its 64 preds,
// emits per-column partial argmax (packed u64) and per-row argmax index.
__global__ __launch_bounds__(256) void mm_argmax_kernel(
    const float* __restrict__ qg,   // feats1 [B][L][CD]  (queries)
    const float* __restrict__ pg,   // feats2 [B][L][CD]  (preds)
    unsigned long long* __restrict__ colpart,  // [B][RT_PER_B][L] packed (enc(val)<<32)|~a
    int* __restrict__ max2)                    // [B][L] argmax_j per pred row
{
    __shared__ __bf16 sP[TM][CD + 8];       // +8 bf16 pad: b128 frag reads 2-way (free)
    __shared__ __bf16 sQ[TN][KCHUNK + 8];
    __shared__ unsigned long long sCol[TN];
    __shared__ unsigned long long sRow[TM];

    const int tid  = threadIdx.x;
    const int b    = blockIdx.x >> 4;
    const int rt   = blockIdx.x & 15;
    const int row0 = rt * TM;

    const int lane = tid & 63;
    const int w    = tid >> 6;       // wave 0..3
    const int wm   = w >> 1;         // wave row (2x2 wave grid, each wave 32x32)
    const int wn   = w & 1;          // wave col
    const int quad = lane >> 4;
    const int l16  = lane & 15;

    const float* pB = pg + ((size_t)b * L + row0) * CD;
    const float* qB = qg + (size_t)b * L * CD;

    // ---- stage P tile (64 x 256) fp32 -> bf16 LDS, once per block ----
    {
        const int r  = tid >> 2;          // 0..63
        const int f0 = (tid & 3) * 16;    // float4 slot base (16 per thread)
        const float4* src = (const float4*)(pB + r * CD);
        #pragma unroll
        for (int i = 0; i < 16; ++i) {
            float4 v = src[f0 + i];
            bf16x4 o;
            o[0] = (__bf16)v.x; o[1] = (__bf16)v.y; o[2] = (__bf16)v.z; o[3] = (__bf16)v.w;
            *(bf16x4*)&sP[r][(f0 + i) * 4] = o;
        }
    }
    // visibility of sP covered by the sync after the first q-stage below

    unsigned long long rowbest[2][4];
    #pragma unroll
    for (int tm = 0; tm < 2; ++tm)
        #pragma unroll
        for (int r = 0; r < 4; ++r) rowbest[tm][r] = 0ull;  // below any finite encoding

    for (int nt = 0; nt < 16; ++nt) {
        f32x4 acc[2][2];
        #pragma unroll
        for (int tm = 0; tm < 2; ++tm)
            #pragma unroll
            for (int tn = 0; tn < 2; ++tn)
                acc[tm][tn] = (f32x4){0.f, 0.f, 0.f, 0.f};

        for (int kc = 0; kc < 2; ++kc) {
            __syncthreads();   // protect sQ (readers of previous chunk done)
            // ---- stage Q chunk (64 rows x 128 k) ----
            {
                const int r  = tid >> 2;
                const int f0 = (tid & 3) * 8;
                const float4* src = (const float4*)(qB + (size_t)(nt * TN + r) * CD + kc * KCHUNK);
                #pragma unroll
                for (int i = 0; i < 8; ++i) {
                    float4 v = src[f0 + i];
                    bf16x4 o;
                    o[0] = (__bf16)v.x; o[1] = (__bf16)v.y; o[2] = (__bf16)v.z; o[3] = (__bf16)v.w;
                    *(bf16x4*)&sQ[r][(f0 + i) * 4] = o;
                }
            }
            __syncthreads();
            #pragma unroll
            for (int kk = 0; kk < 4; ++kk) {
                const int ka = kc * KCHUNK + kk * 32 + quad * 8;  // k offset in sP
                const int kb = kk * 32 + quad * 8;                // k offset in sQ (chunk-local)
                // A frag: lane holds A[m=l16][k=quad*8+j]; B frag symmetric on q rows
                bf16x8 a0 = *(const bf16x8*)&sP[wm * 32 +      l16][ka];
                bf16x8 a1 = *(const bf16x8*)&sP[wm * 32 + 16 + l16][ka];
                bf16x8 b0 = *(const bf16x8*)&sQ[wn * 32 +      l16][kb];
                bf16x8 b1 = *(const bf16x8*)&sQ[wn * 32 + 16 + l16][kb];
                acc[0][0] = __builtin_amdgcn_mfma_f32_16x16x32_bf16(a0, b0, acc[0][0], 0, 0, 0);
                acc[0][1] = __builtin_amdgcn_mfma_f32_16x16x32_bf16(a0, b1, acc[0][1], 0, 0, 0);
                acc[1][0] = __builtin_amdgcn_mfma_f32_16x16x32_bf16(a1, b0, acc[1][0], 0, 0, 0);
                acc[1][1] = __builtin_amdgcn_mfma_f32_16x16x32_bf16(a1, b1, acc[1][1], 0, 0, 0);
            }
        }

        // ---- column partial argmax over this block's 64 rows ----
        // C/D layout: col = l16, row = quad*4 + reg  (m89/m91 verified)
        unsigned long long cpk0 = 0ull, cpk1 = 0ull;
        #pragma unroll
        for (int tm = 0; tm < 2; ++tm) {
            #pragma unroll
            for (int r = 0; r < 4; ++r) {
                const unsigned int aidx = (unsigned int)(row0 + wm * 32 + tm * 16 + quad * 4 + r);
                unsigned long long p0 = ((unsigned long long)enc_f32(acc[tm][0][r]) << 32) | (unsigned int)(~aidx);
                unsigned long long p1 = ((unsigned long long)enc_f32(acc[tm][1][r]) << 32) | (unsigned int)(~aidx);
                cpk0 = pmax(cpk0, p0);
                cpk1 = pmax(cpk1, p1);
            }
        }
        cpk0 = pmax(cpk0, __shfl_xor(cpk0, 16));
        cpk0 = pmax(cpk0, __shfl_xor(cpk0, 32));
        cpk1 = pmax(cpk1, __shfl_xor(cpk1, 16));
        cpk1 = pmax(cpk1, __shfl_xor(cpk1, 32));
        __syncthreads();
        if (wm == 0) {
            if (quad == 0)      sCol[wn * 32 +      l16] = cpk0;
            else if (quad == 1) sCol[wn * 32 + 16 + l16] = cpk1;
        }
        __syncthreads();
        if (wm == 1) {
            if (quad == 0) {
                const int j = nt * TN + wn * 32 + l16;
                colpart[((size_t)b * RT_PER_B + rt) * L + j] = pmax(cpk0, sCol[wn * 32 + l16]);
            } else if (quad == 1) {
                const int j = nt * TN + wn * 32 + 16 + l16;
                colpart[((size_t)b * RT_PER_B + rt) * L + j] = pmax(cpk1, sCol[wn * 32 + 16 + l16]);
            }
        }

        // ---- row running argmax over columns (packed; ~j => smallest j wins ties) ----
        {
            const unsigned int j0 = (unsigned int)(nt * TN + wn * 32 + l16);
            const unsigned int j1 = j0 + 16;
            #pragma unroll
            for (int tm = 0; tm < 2; ++tm) {
                #pragma unroll
                for (int r = 0; r < 4; ++r) {
                    unsigned long long p0 = ((unsigned long long)enc_f32(acc[tm][0][r]) << 32) | (unsigned int)(~j0);
                    unsigned long long p1 = ((unsigned long long)enc_f32(acc[tm][1][r]) << 32) | (unsigned int)(~j1);
                    rowbest[tm][r] = pmax(rowbest[tm][r], pmax(p0, p1));
                }
            }
        }
    }

    // ---- finalize row argmax: reduce across the 16 column-lanes, then across wn ----
    unsigned long long rr[2][4];
    #pragma unroll
    for (int tm = 0; tm < 2; ++tm) {
        #pragma unroll
        for (int r = 0; r < 4; ++r) {
            unsigned long long pk = rowbest[tm][r];
            pk = pmax(pk, __shfl_xor(pk, 1));
            pk = pmax(pk, __shfl_xor(pk, 2));
            pk = pmax(pk, __shfl_xor(pk, 4));
            pk = pmax(pk, __shfl_xor(pk, 8));
            rr[tm][r] = pk;
        }
    }
    __syncthreads();
    if (wn == 0 && l16 == 0) {
        #pragma unroll
        for (int tm = 0; tm < 2; ++tm)
            #pragma unroll
            for (int r = 0; r < 4; ++r)
                sRow[wm * 32 + tm * 16 + quad * 4 + r] = rr[tm][r];
    }
    __syncthreads();
    if (wn == 1 && l16 == 0) {
        #pragma unroll
        for (int tm = 0; tm < 2; ++tm) {
            #pragma unroll
            for (int r = 0; r < 4; ++r) {
                const int a = wm * 32 + tm * 16 + quad * 4 + r;
                unsigned long long m = pmax(rr[tm][r], sRow[a]);
                max2[(size_t)b * L + row0 + a] = (int)(~(unsigned int)m);
            }
        }
    }
}

// Kernel 2: per-batch final reduction — combine colpart over row-tiles,
// mutual-NN check, masked mean.
__global__ __launch_bounds__(256) void finalize_kernel(
    const unsigned long long* __restrict__ colpart,
    const int* __restrict__ max2,
    float* __restrict__ out)
{
    __shared__ int sMax2[L];
    __shared__ float sSum[4];
    __shared__ int sCnt[4];
    const int b = blockIdx.x;
    const int tid = threadIdx.x;

    for (int i = tid; i < L; i += 256) sMax2[i] = max2[(size_t)b * L + i];
    __syncthreads();

    float sum = 0.f;
    int cnt = 0;
    #pragma unroll
    for (int i = 0; i < 4; ++i) {
        const int j = tid + i * 256;
        unsigned long long best = 0ull;
        #pragma unroll
        for (int rt = 0; rt < RT_PER_B; ++rt)
            best = pmax(best, colpart[((size_t)b * RT_PER_B + rt) * L + j]);
        const int a = (int)(~(unsigned int)best);              // max1[j]
        const float val = dec_f32((unsigned int)(best >> 32)); // sims[j] = col max value
        if (sMax2[a] == j) { sum += val; ++cnt; }              // mutual NN
    }
    #pragma unroll
    for (int o = 32; o >= 1; o >>= 1) {
        sum += __shfl_down(sum, o);
        cnt += __shfl_down(cnt, o);
    }
    if ((tid & 63) == 0) { sSum[tid >> 6] = sum; sCnt[tid >> 6] = cnt; }
    __syncthreads();
    if (tid == 0) {
        float S = sSum[0] + sSum[1] + sSum[2] + sSum[3];
        int   C = sCnt[0] + sCnt[1] + sCnt[2] + sCnt[3];
        out[b] = S / fmaxf((float)C, 1.0f);
    }
}

extern "C" void kernel_launch(void* const* d_in, const int* in_sizes, int n_in,
                              void* d_out, int out_size, void* d_ws, size_t ws_size,
                              hipStream_t stream) {
    const float* q = (const float*)d_in[0];   // feats1
    const float* p = (const float*)d_in[1];   // feats2
    float* out = (float*)d_out;

    // ws layout: colpart [32][16][1024] u64 = 4 MiB, then max2 [32][1024] int = 128 KiB.
    // Every slot is written by kernel 1 before kernel 2 reads it -> no init needed.
    unsigned long long* colpart = (unsigned long long*)d_ws;
    int* max2 = (int*)((char*)d_ws + (size_t)BATCH * RT_PER_B * L * sizeof(unsigned long long));

    mm_argmax_kernel<<<BATCH * RT_PER_B, 256, 0, stream>>>(q, p, colpart, max2);
    finalize_kernel<<<BATCH, 256, 0, stream>>>(colpart, max2, out);
}